// Round 17
// baseline (250.191 us; speedup 1.0000x reference)
//
#include <hip/hip_runtime.h>

typedef _Float16 hp2 __attribute__((ext_vector_type(2)));

#define NB    1024
#define TT    256
#define EE    100
#define VOCAB 5000
#define GG1   256   // 4*H1
#define GG2   128   // 4*H2

__device__ __forceinline__ float fast_sigmoid(float x) {
  return __builtin_amdgcn_rcpf(1.0f + __expf(-x));
}
__device__ __forceinline__ float fast_tanh(float x) {
  return 1.0f - 2.0f * __builtin_amdgcn_rcpf(1.0f + __expf(2.0f * x));
}

// Counted-wait barrier: drain LDS only; global zx prefetch stays in flight.
__device__ __forceinline__ void step_sync() {
  asm volatile("s_waitcnt lgkmcnt(0)" ::: "memory");
  __builtin_amdgcn_s_barrier();
  __builtin_amdgcn_sched_barrier(0);
}

// ---- K1: emb_zi[v][u*4+g] = b1[g*64+u] + sum_k emb[v][k]*W1[k][g*64+u] ----
__global__ __launch_bounds__(256) void emb_gemm(
    const float* __restrict__ emb, const float* __restrict__ W1,
    const float* __restrict__ b1, float* __restrict__ emb_zi)
{
  __shared__ float sE[8][EE];
  const int j  = threadIdx.x;           // column g*64+u
  const int v0 = blockIdx.x * 8;
  for (int idx = j; idx < 8 * EE; idx += 256) {
    int r = idx / EE, k = idx % EE;
    sE[r][k] = emb[(size_t)(v0 + r) * EE + k];
  }
  __syncthreads();
  float acc[8];
  const float bb = b1[j];
  #pragma unroll
  for (int r = 0; r < 8; ++r) acc[r] = bb;
  for (int k = 0; k < EE; ++k) {
    float w = W1[k * GG1 + j];
    #pragma unroll
    for (int r = 0; r < 8; ++r) acc[r] = fmaf(sE[r][k], w, acc[r]);
  }
  const int slot = (j & 63) * 4 + (j >> 6);   // u*4 + g
  #pragma unroll
  for (int r = 0; r < 8; ++r) emb_zi[(size_t)(v0 + r) * GG1 + slot] = acc[r];
}

// ---- K2: one block = one row, FOUR waves (gate-split), 2 phases/step ----
// w0: L1 gates i,f  (64 fdot2) -> writes raw partial float2 pL1[u]
// w1: L1 gates g,o  (64 fdot2) -> finisher: +zx, acts, owns c1/h1, writes sH
// w2: L2 gates i,f  (48 fdot2 + shfl32) -> writes partial float2 pL2[u2]
// w3: L2 gates g,o  (48 fdot2 + shfl32) -> finisher: +bias, owns c2/h2
// Single h-buffer sH[96] (reads phase-1, writes phase-2, barrier-separated).
// 1024 blocks x 4 waves = 4 waves/SIMD; waves_per_eu(4,4) = 128-reg budget.
__global__ __launch_bounds__(256) __attribute__((amdgpu_waves_per_eu(4, 4)))
void lstm_quad(
    const int* __restrict__ tokens, const float* __restrict__ emb_zi,
    const float* __restrict__ U1,
    const float* __restrict__ W2, const float* __restrict__ U2, const float* __restrict__ b2,
    const float* __restrict__ Wd, const float* __restrict__ bd,
    float* __restrict__ out)
{
  __shared__ __align__(16) _Float16 sH[96];   // 0..63 h1, 64..95 h2
  __shared__ __align__(8) float2 pL1[64];
  __shared__ __align__(8) float2 pL2[32];
  __shared__ int sTok[TT];

  const int tid = threadIdx.x;
  const int u   = tid & 63;
  const int wv  = tid >> 6;           // wave role 0..3
  const int row = blockIdx.x;
  const int u2  = u & 31;             // L2 unit
  const int s   = u >> 5;             // L2 k-half
  const int g0  = (wv & 1) * 2;       // gate base: waves 0,2 -> {0,1}; 1,3 -> {2,3}

  // ---- stage tokens + zero sH ----
  if (tid < 128) ((int2*)sTok)[tid] = ((const int2*)(tokens + (size_t)row * TT))[tid];
  if (tid < 96) sH[tid] = (_Float16)0.0f;

  // ---- weights: 2 gates per wave ----
  hp2 wW[64];   // L1 waves: wW[2p+e] = {U1[2p][.], U1[2p+1][.]} col (g0+e)*64+u
                // L2 waves: wW[2p+e] = combined [W2;U2] k-pair, col (g0+e)*32+u2
  if (wv < 2) {
    #pragma unroll
    for (int p = 0; p < 32; ++p) {
      #pragma unroll
      for (int e = 0; e < 2; ++e) {
        hp2 w;
        w[0] = (_Float16)U1[(2 * p + 0) * GG1 + (g0 + e) * 64 + u];
        w[1] = (_Float16)U1[(2 * p + 1) * GG1 + (g0 + e) * 64 + u];
        wW[2 * p + e] = w;
      }
    }
  } else {
    #pragma unroll
    for (int p = 0; p < 24; ++p) {
      int k0 = 48 * s + 2 * p;        // even: never straddles the 64 boundary
      const float* r0 = (k0     < 64) ? &W2[(size_t)k0 * GG2]       : &U2[(size_t)(k0 - 64) * GG2];
      const float* r1 = (k0 + 1 < 64) ? &W2[(size_t)(k0 + 1) * GG2] : &U2[(size_t)(k0 + 1 - 64) * GG2];
      #pragma unroll
      for (int e = 0; e < 2; ++e) {
        hp2 w;
        w[0] = (_Float16)r0[(g0 + e) * 32 + u2];
        w[1] = (_Float16)r1[(g0 + e) * 32 + u2];
        wW[2 * p + e] = w;
      }
    }
  }
  const float bga = b2[g0 * 32 + u2];       // biases for this wave's 2 gates (L2)
  const float bgb = b2[(g0 + 1) * 32 + u2];
  __syncthreads();

  float c1 = 0.f, h1r = 0.f;          // live in w1
  float c2 = 0.f, h2r = 0.f;          // live in w3 (both lanes redundant)

  // ---- prologue (w1): h1(0) from zx(0); h1(-1)=0 so dots are zero ----
  if (wv == 1) {
    int tok0 = sTok[0];
    float4 zx0 = *(const float4*)&emb_zi[(size_t)tok0 * GG1 + 4 * u];
    if (tok0 != 0) {
      float iv = fast_sigmoid(zx0.x);
      float gv = fast_tanh(zx0.z);
      float ov = fast_sigmoid(zx0.w);
      c1 = iv * gv; h1r = ov * fast_tanh(c1);
    }
    sH[u] = (_Float16)h1r;
  }
  // w1's zx for step t+1 = 1 (prefetched; rides across barriers)
  int   tok_a = 0;
  float4 zxa = {0.f, 0.f, 0.f, 0.f};
  if (wv == 1) {
    tok_a = sTok[1];
    zxa = *(const float4*)&emb_zi[(size_t)tok_a * GG1 + 4 * u];
  }
  step_sync();

  for (int t = 0; t < TT; ++t) {
    // ================= phase 1: dots from sH = {h1(t), h2(t-1)} =============
    if (wv < 2) {
      if (t + 1 < TT) {
        float da = 0.f, db = 0.f;               // this wave's 2 gate dots
        const int4* rb = (const int4*)&sH[0];
        #pragma unroll
        for (int q = 0; q < 8; ++q) {           // uniform b128 broadcast reads
          int4 hq = rb[q];
          #pragma unroll
          for (int pp = 0; pp < 4; ++pp) {
            const int p = 4 * q + pp;
            hp2 hv = ((const hp2*)&hq)[pp];
            da = __builtin_amdgcn_fdot2(hv, wW[2 * p + 0], da, false);
            db = __builtin_amdgcn_fdot2(hv, wW[2 * p + 1], db, false);
          }
        }
        if (wv == 0) {
          pL1[u] = make_float2(da, db);         // raw i,f partials
        } else {
          // w1: keep g,o; prefetch zx(t+2) now (covers both barriers)
          float zg = da, zo = db;
          int tok_n = 0;
          if (t + 2 < TT) {
            tok_n = sTok[t + 2];
          }
          float4 zxn = zxa;
          if (t + 2 < TT)
            zxn = *(const float4*)&emb_zi[(size_t)tok_n * GG1 + 4 * u];
          step_sync();                          // ---- phase boundary ----
          // ================= phase 2 (w1): finish h1(t+1) =================
          float2 pif = pL1[u];
          const bool ma = (tok_a != 0);
          float iv = fast_sigmoid(pif.x + zxa.x);
          float fv = fast_sigmoid(pif.y + zxa.y);
          float gv = fast_tanh(zg + zxa.z);
          float ov = fast_sigmoid(zo + zxa.w);
          if (ma) { c1 = fv * c1 + iv * gv; h1r = ov * fast_tanh(c1); }
          sH[u] = (_Float16)h1r;
          tok_a = tok_n; zxa = zxn;
          step_sync();
          continue;                             // w1 handled both barriers
        }
      }
    } else {
      float da = 0.f, db = 0.f;
      const int4* hbp = (const int4*)(&sH[48 * s]);   // 2 addrs/wave: free
      #pragma unroll
      for (int q = 0; q < 6; ++q) {
        int4 hq = hbp[q];
        #pragma unroll
        for (int pp = 0; pp < 4; ++pp) {
          const int p = 4 * q + pp;
          hp2 hv = ((const hp2*)&hq)[pp];
          da = __builtin_amdgcn_fdot2(hv, wW[2 * p + 0], da, false);
          db = __builtin_amdgcn_fdot2(hv, wW[2 * p + 1], db, false);
        }
      }
      da += __shfl_xor(da, 32);                 // full-k sums, both lanes
      db += __shfl_xor(db, 32);
      if (wv == 2) {
        if (s == 0) pL2[u2] = make_float2(da, db);
      } else {
        // w3: finisher for h2(t)
        const int tok_b = sTok[t];
        step_sync();                            // ---- phase boundary ----
        float2 pif = pL2[u2];
        const bool mb = (tok_b != 0);
        float i2 = fast_sigmoid(pif.x + bga);
        float f2 = fast_sigmoid(pif.y + bgb);
        float g2 = fast_tanh(da + bga - bga + b2[64 + u2]);  // z_g + its bias
        float o2 = fast_sigmoid(db + b2[96 + u2]);
        if (mb) { c2 = f2 * c2 + i2 * g2; h2r = o2 * fast_tanh(c2); }
        if (s == 0) sH[64 + u2] = (_Float16)h2r;
        step_sync();
        continue;
      }
    }
    step_sync();                                // phase boundary (w0, w2, idle w1@last)
    step_sync();                                // end of phase 2
  }
  __syncthreads();

  // ---- epilogue: out = sigmoid(h2 @ Wd + bd) ----
  if (tid < 4) {
    float a = bd[tid];
    #pragma unroll
    for (int k = 0; k < 32; ++k)
      a = fmaf((float)sH[64 + k], Wd[k * 4 + tid], a);
    out[(size_t)row * 4 + tid] = fast_sigmoid(a);
  }
}

extern "C" void kernel_launch(void* const* d_in, const int* in_sizes, int n_in,
                              void* d_out, int out_size, void* d_ws, size_t ws_size,
                              hipStream_t stream) {
  const int*   tokens = (const int*)d_in[0];
  const float* emb    = (const float*)d_in[1];
  const float* W1     = (const float*)d_in[2];
  const float* U1     = (const float*)d_in[3];
  const float* b1     = (const float*)d_in[4];
  const float* W2     = (const float*)d_in[5];
  const float* U2     = (const float*)d_in[6];
  const float* b2     = (const float*)d_in[7];
  const float* Wd     = (const float*)d_in[8];
  const float* bd     = (const float*)d_in[9];
  float* out    = (float*)d_out;
  float* emb_zi = (float*)d_ws;         // 5000*256*4 = 5.12 MB scratch

  emb_gemm<<<dim3(VOCAB / 8), dim3(256), 0, stream>>>(emb, W1, b1, emb_zi);
  lstm_quad<<<dim3(NB), dim3(256), 0, stream>>>(
      tokens, emb_zi, U1, W2, U2, b2, Wd, bd, out);
}

// Round 18
// 240.167 us; speedup vs baseline: 1.0417x; 1.0417x over previous
//
#include <hip/hip_runtime.h>

typedef _Float16 hp2 __attribute__((ext_vector_type(2)));

#define NB    1024
#define TT    256
#define EE    100
#define VOCAB 5000
#define GG1   256   // 4*H1
#define GG2   128   // 4*H2

__device__ __forceinline__ float fast_sigmoid(float x) {
  return __builtin_amdgcn_rcpf(1.0f + __expf(-x));
}
__device__ __forceinline__ float fast_tanh(float x) {
  return 1.0f - 2.0f * __builtin_amdgcn_rcpf(1.0f + __expf(2.0f * x));
}
__device__ __forceinline__ float hsum2(hp2 v) {   // packed f16 acc -> f32
  return (float)v[0] + (float)v[1];
}

// Counted-wait barrier: drain LDS ops only; global (zx prefetch) stays in flight.
__device__ __forceinline__ void step_sync() {
  asm volatile("s_waitcnt lgkmcnt(0)" ::: "memory");
  __builtin_amdgcn_s_barrier();
  __builtin_amdgcn_sched_barrier(0);
}

// ---- K1: emb_zi[v][u*4+g] = b1[g*64+u] + sum_k emb[v][k]*W1[k][g*64+u] ----
__global__ __launch_bounds__(256) void emb_gemm(
    const float* __restrict__ emb, const float* __restrict__ W1,
    const float* __restrict__ b1, float* __restrict__ emb_zi)
{
  __shared__ float sE[8][EE];
  const int j  = threadIdx.x;           // column g*64+u
  const int v0 = blockIdx.x * 8;
  for (int idx = j; idx < 8 * EE; idx += 256) {
    int r = idx / EE, k = idx % EE;
    sE[r][k] = emb[(size_t)(v0 + r) * EE + k];
  }
  __syncthreads();
  float acc[8];
  const float bb = b1[j];
  #pragma unroll
  for (int r = 0; r < 8; ++r) acc[r] = bb;
  for (int k = 0; k < EE; ++k) {
    float w = W1[k * GG1 + j];
    #pragma unroll
    for (int r = 0; r < 8; ++r) acc[r] = fmaf(sE[r][k], w, acc[r]);
  }
  const int slot = (j & 63) * 4 + (j >> 6);   // u*4 + g
  #pragma unroll
  for (int r = 0; r < 8; ++r) emb_zi[(size_t)(v0 + r) * GG1 + slot] = acc[r];
}

// ---- K2: one block = one row, TWO waves (wave0 = L1, wave1 = L2) ----
// Round-16 structure verbatim; the ONLY change: dot chains use v_pk_fma_f16
// (packed f16 accumulate, one f32 combine per gate) instead of v_dot2_f32_f16.
__global__ __launch_bounds__(128) __attribute__((amdgpu_waves_per_eu(2, 2)))
void lstm_dual(
    const int* __restrict__ tokens, const float* __restrict__ emb_zi,
    const float* __restrict__ U1,
    const float* __restrict__ W2, const float* __restrict__ U2, const float* __restrict__ b2,
    const float* __restrict__ Wd, const float* __restrict__ bd,
    float* __restrict__ out)
{
  __shared__ __align__(16) _Float16 sHB[2][96];  // 0..63 h1, 64..95 h2
  __shared__ int sTok[TT];

  const int tid = threadIdx.x;
  const int u   = tid & 63;
  const int wv  = tid >> 6;           // 0: L1 wave, 1: L2 wave
  const int row = blockIdx.x;

  // ---- stage tokens + zero h buffers ----
  ((int2*)sTok)[tid] = ((const int2*)(tokens + (size_t)row * TT))[tid];
  if (tid < 96) { sHB[0][tid] = (_Float16)0.0f; sHB[1][tid] = (_Float16)0.0f; }

  if (wv == 0) {
    // ================= L1 wave: lane u owns unit u =================
    hp2 wA[128];   // wA[4p+g] = {U1[2p][g*64+u], U1[2p+1][g*64+u]}, p=0..31
    #pragma unroll
    for (int p = 0; p < 32; ++p) {
      #pragma unroll
      for (int g = 0; g < 4; ++g) {
        hp2 w;
        w[0] = (_Float16)U1[(2 * p + 0) * GG1 + g * 64 + u];
        w[1] = (_Float16)U1[(2 * p + 1) * GG1 + g * 64 + u];
        wA[4 * p + g] = w;
      }
    }
    __syncthreads();                  // tokens + zeroed buffers visible

    float c1 = 0.f, h1r = 0.f;
    // ---- prologue: h1(0) from zx(0) (h1(-1)=0), write parity 0 ----
    {
      int tok0 = sTok[0];
      float4 zx0 = *(const float4*)&emb_zi[(size_t)tok0 * GG1 + 4 * u];
      if (tok0 != 0) {
        float iv = fast_sigmoid(zx0.x);
        float gv = fast_tanh(zx0.z);
        float ov = fast_sigmoid(zx0.w);
        c1 = iv * gv; h1r = ov * fast_tanh(c1);
      }
      sHB[0][u] = (_Float16)h1r;
    }
    int   tok_a = sTok[1];            // token for A-step t+1 = 1
    float4 zxa = *(const float4*)&emb_zi[(size_t)tok_a * GG1 + 4 * u];
    step_sync();                      // pairs with wave1's first sync

    for (int t = 0; t < TT; ++t) {
      if (t + 1 < TT) {               // ---- A(t+1): h1(t+1) from h1(t) ----
        hp2 q0 = {(_Float16)0.f, (_Float16)0.f};
        hp2 q1 = q0, q2 = q0, q3 = q0;
        // prefetch zx(t+2): rides across the barrier (counted wait)
        int tok_n = 0;
        if (t + 2 < TT) {
          tok_n = sTok[t + 2];
          zxa = *(const float4*)&emb_zi[(size_t)tok_n * GG1 + 4 * u];
        }
        float4 zcur = zxa;            // NOTE: zxa was consumed into zcur BEFORE
        // (careful ordering below: zcur must be the t+1 value)
        // -- we saved zxa into registers a-combine later; re-read pattern kept
        // identical to round 16 by staging zcur first:
        (void)zcur;
        const int4* rb = (const int4*)&sHB[t & 1][0];
        #pragma unroll
        for (int q = 0; q < 8; ++q) {           // uniform b128 broadcast reads
          int4 hq = rb[q];
          #pragma unroll
          for (int pp = 0; pp < 4; ++pp) {
            const int p = 4 * q + pp;
            hp2 hv = ((const hp2*)&hq)[pp];
            q0 = __builtin_elementwise_fma(hv, wA[4 * p + 0], q0);
            q1 = __builtin_elementwise_fma(hv, wA[4 * p + 1], q1);
            q2 = __builtin_elementwise_fma(hv, wA[4 * p + 2], q2);
            q3 = __builtin_elementwise_fma(hv, wA[4 * p + 3], q3);
          }
        }
        {
          const bool ma = (tok_a != 0);
          float iv = fast_sigmoid(hsum2(q0) + zcur.x);
          float fv = fast_sigmoid(hsum2(q1) + zcur.y);
          float gv = fast_tanh(hsum2(q2) + zcur.z);
          float ov = fast_sigmoid(hsum2(q3) + zcur.w);
          if (ma) { c1 = fv * c1 + iv * gv; h1r = ov * fast_tanh(c1); }
        }
        sHB[(t & 1) ^ 1][u] = (_Float16)h1r;
        tok_a = tok_n;
      }
      step_sync();
    }
  } else {
    // ================= L2 wave: unit u2 = u&31, k-half s = u>>5 =================
    const int u2 = u & 31;
    const int s  = u >> 5;
    hp2 wB[96];    // wB[4p+g] = {[W2;U2][k0][g*32+u2], [k0+1][...]}, k0 = 48s+2p
    #pragma unroll
    for (int p = 0; p < 24; ++p) {
      int k0 = 48 * s + 2 * p;        // even: never straddles the 64 boundary
      const float* r0 = (k0     < 64) ? &W2[(size_t)k0 * GG2]       : &U2[(size_t)(k0 - 64) * GG2];
      const float* r1 = (k0 + 1 < 64) ? &W2[(size_t)(k0 + 1) * GG2] : &U2[(size_t)(k0 + 1 - 64) * GG2];
      #pragma unroll
      for (int g = 0; g < 4; ++g) {
        hp2 w;
        w[0] = (_Float16)r0[g * 32 + u2];
        w[1] = (_Float16)r1[g * 32 + u2];
        wB[4 * p + g] = w;
      }
    }
    const float bi2 = b2[u2], bf2 = b2[32 + u2], bg2 = b2[64 + u2], bo2 = b2[96 + u2];
    __syncthreads();                  // tokens + zeroed buffers visible

    float c2 = 0.f, h2r = 0.f;
    step_sync();                      // pairs with wave0's prologue sync

    for (int t = 0; t < TT; ++t) {
      // ---- B(t): h2(t) from [h1(t) | h2(t-1)] at parity t&1 ----
      const int tok_b = sTok[t];
      hp2 q0 = {(_Float16)0.f, (_Float16)0.f};
      hp2 q1 = q0, q2 = q0, q3 = q0;
      const int4* hbp = (const int4*)(&sHB[t & 1][48 * s]);  // 2 addrs/wave
      #pragma unroll
      for (int q = 0; q < 6; ++q) {
        int4 hq = hbp[q];
        #pragma unroll
        for (int pp = 0; pp < 4; ++pp) {
          const int p = 4 * q + pp;
          hp2 hv = ((const hp2*)&hq)[pp];
          q0 = __builtin_elementwise_fma(hv, wB[4 * p + 0], q0);
          q1 = __builtin_elementwise_fma(hv, wB[4 * p + 1], q1);
          q2 = __builtin_elementwise_fma(hv, wB[4 * p + 2], q2);
          q3 = __builtin_elementwise_fma(hv, wB[4 * p + 3], q3);
        }
      }
      float b0  = hsum2(q0);
      float b1v = hsum2(q1);
      float b2v = hsum2(q2);
      float b3  = hsum2(q3);
      b0  += __shfl_xor(b0, 32);
      b1v += __shfl_xor(b1v, 32);
      b2v += __shfl_xor(b2v, 32);
      b3  += __shfl_xor(b3, 32);
      {
        const bool mb = (tok_b != 0);
        float i2 = fast_sigmoid(b0 + bi2);
        float f2 = fast_sigmoid(b1v + bf2);
        float g2 = fast_tanh(b2v + bg2);
        float o2 = fast_sigmoid(b3 + bo2);
        if (mb) { c2 = f2 * c2 + i2 * g2; h2r = o2 * fast_tanh(c2); }
      }
      if (s == 0) sHB[(t & 1) ^ 1][64 + u2] = (_Float16)h2r;
      step_sync();
    }
  }
  __syncthreads();

  // ---- epilogue: h2(TT-1) in parity ((TT-1)&1)^1 = 0 ----
  if (tid < 4) {
    float a = bd[tid];
    #pragma unroll
    for (int k = 0; k < 32; ++k)
      a = fmaf((float)sHB[0][64 + k], Wd[k * 4 + tid], a);
    out[(size_t)row * 4 + tid] = fast_sigmoid(a);
  }
}

extern "C" void kernel_launch(void* const* d_in, const int* in_sizes, int n_in,
                              void* d_out, int out_size, void* d_ws, size_t ws_size,
                              hipStream_t stream) {
  const int*   tokens = (const int*)d_in[0];
  const float* emb    = (const float*)d_in[1];
  const float* W1     = (const float*)d_in[2];
  const float* U1     = (const float*)d_in[3];
  const float* b1     = (const float*)d_in[4];
  const float* W2     = (const float*)d_in[5];
  const float* U2     = (const float*)d_in[6];
  const float* b2     = (const float*)d_in[7];
  const float* Wd     = (const float*)d_in[8];
  const float* bd     = (const float*)d_in[9];
  float* out    = (float*)d_out;
  float* emb_zi = (float*)d_ws;         // 5000*256*4 = 5.12 MB scratch

  emb_gemm<<<dim3(VOCAB / 8), dim3(256), 0, stream>>>(emb, W1, b1, emb_zi);
  lstm_dual<<<dim3(NB), dim3(128), 0, stream>>>(
      tokens, emb_zi, U1, W2, U2, b2, Wd, bd, out);
}